// Round 2
// baseline (5135.337 us; speedup 1.0000x reference)
//
#include <hip/hip_runtime.h>
#include <hip/hip_bf16.h>

#define NFEAT 256
#define NHID  128
#define NCLS  10
#define CONV_TIME 30

// ---------------------------------------------------------------- degree histogram
// NOTE: harness stages integer inputs as int32 (NOT int64) — read as int.
__global__ void deg_kernel(const int* __restrict__ ei, int* __restrict__ cnt, int E) {
    int e = blockIdx.x * blockDim.x + threadIdx.x;
    if (e < E) {
        int d = ei[(size_t)E + e];   // edge_index[1][e]
        atomicAdd(&cnt[d], 1);
    }
}

// ---------------------------------------------------------------- dinv = 1/sqrt(deg+1)
__global__ void dinv_kernel(const int* __restrict__ cnt, float* __restrict__ dinv, int n) {
    int i = blockIdx.x * blockDim.x + threadIdx.x;
    if (i < n) {
        float deg = (float)(cnt[i] + 1);   // +1 self loop; always >= 1
        dinv[i] = 1.0f / sqrtf(deg);
    }
}

// ---------------------------------------------------------------- exclusive scan (single block)
__global__ void scan_kernel(const int* __restrict__ cnt, int* __restrict__ offs,
                            int* __restrict__ pos, int n) {
    __shared__ int lds[256];
    int tid = threadIdx.x;
    int per = (n + 255) >> 8;
    int beg = tid * per;
    int end = min(beg + per, n);
    int sum = 0;
    for (int i = beg; i < end; ++i) sum += cnt[i];
    lds[tid] = sum;
    __syncthreads();
    if (tid == 0) {
        int acc = 0;
        for (int i = 0; i < 256; ++i) { int t = lds[i]; lds[i] = acc; acc += t; }
    }
    __syncthreads();
    int run = lds[tid];
    for (int i = beg; i < end; ++i) { offs[i] = run; pos[i] = run; run += cnt[i]; }
    if (tid == 255) offs[n] = run;   // total edge count
}

// ---------------------------------------------------------------- scatter edges into CSR (by dst)
__global__ void scatter_kernel(const int* __restrict__ ei, const float* __restrict__ dinv,
                               int* __restrict__ pos, int* __restrict__ esrc,
                               float* __restrict__ enorm, int E) {
    int e = blockIdx.x * blockDim.x + threadIdx.x;
    if (e < E) {
        int s = ei[e];
        int d = ei[(size_t)E + e];
        int p = atomicAdd(&pos[d], 1);
        esrc[p]  = s;
        enorm[p] = dinv[s] * dinv[d];
    }
}

// ---------------------------------------------------------------- h0 = x @ W1 + b1  (fp32, tiled)
// block = 256 threads, tile 64(M) x 128(N), K-chunks of 16
__global__ __launch_bounds__(256) void gemm1_kernel(const float* __restrict__ x,
                                                    const float* __restrict__ W1,
                                                    const float* __restrict__ b1,
                                                    float* __restrict__ h, int M) {
    __shared__ float As[64][20];    // padded row stride (80B, 16B-aligned)
    __shared__ float Bs[16][128];
    int tid = threadIdx.x;
    int m0  = blockIdx.x * 64;
    int tx  = tid & 15;        // 16 col-groups of 8
    int ty  = tid >> 4;        // 16 row-groups of 4
    int ar  = tid >> 2, aq = tid & 3;
    int br  = tid >> 4, bc = tid & 15;

    float acc[4][8];
#pragma unroll
    for (int i = 0; i < 4; ++i)
#pragma unroll
        for (int j = 0; j < 8; ++j) acc[i][j] = 0.0f;

    for (int kb = 0; kb < NFEAT; kb += 16) {
        float4 av = make_float4(0.f, 0.f, 0.f, 0.f);
        int arow = m0 + ar;
        if (arow < M) av = *(const float4*)(x + (size_t)arow * NFEAT + kb + aq * 4);
        *(float4*)&As[ar][aq * 4] = av;
        *(float4*)&Bs[br][bc * 8]     = *(const float4*)(W1 + (size_t)(kb + br) * NHID + bc * 8);
        *(float4*)&Bs[br][bc * 8 + 4] = *(const float4*)(W1 + (size_t)(kb + br) * NHID + bc * 8 + 4);
        __syncthreads();
#pragma unroll
        for (int k = 0; k < 16; ++k) {
            float a0 = As[ty * 4 + 0][k];
            float a1 = As[ty * 4 + 1][k];
            float a2 = As[ty * 4 + 2][k];
            float a3 = As[ty * 4 + 3][k];
            float4 b0 = *(float4*)&Bs[k][tx * 8];
            float4 b1v = *(float4*)&Bs[k][tx * 8 + 4];
            float bv[8] = {b0.x, b0.y, b0.z, b0.w, b1v.x, b1v.y, b1v.z, b1v.w};
            float avv[4] = {a0, a1, a2, a3};
#pragma unroll
            for (int i = 0; i < 4; ++i)
#pragma unroll
                for (int j = 0; j < 8; ++j)
                    acc[i][j] = fmaf(avv[i], bv[j], acc[i][j]);
        }
        __syncthreads();
    }
#pragma unroll
    for (int i = 0; i < 4; ++i) {
        int row = m0 + ty * 4 + i;
        if (row < M) {
#pragma unroll
            for (int j = 0; j < 8; ++j)
                h[(size_t)row * NHID + tx * 8 + j] = acc[i][j] + b1[tx * 8 + j];
        }
    }
}

// ---------------------------------------------------------------- one propagation hop
// one wave64 per node; lane holds features [2*lane, 2*lane+1]
__global__ __launch_bounds__(256) void hop_kernel(const float* __restrict__ hin,
                                                  float* __restrict__ hout,
                                                  const int* __restrict__ offs,
                                                  const int* __restrict__ esrc,
                                                  const float* __restrict__ enorm,
                                                  const float* __restrict__ dinv, int n) {
    int wid  = blockIdx.x * 4 + (threadIdx.x >> 6);
    int lane = threadIdx.x & 63;
    if (wid >= n) return;
    int beg = offs[wid];
    int end = offs[wid + 1];
    const float2* __restrict__ hin2 = (const float2*)hin;
    float2 self = hin2[(size_t)wid * 64 + lane];
    float dv = dinv[wid];
    float w0 = dv * dv;
    float ax = self.x * w0;
    float ay = self.y * w0;
    for (int e = beg; e < end; ++e) {
        int   s = esrc[e];
        float w = enorm[e];
        float2 v = hin2[(size_t)s * 64 + lane];
        ax = fmaf(w, v.x, ax);
        ay = fmaf(w, v.y, ay);
    }
    float2 r; r.x = ax; r.y = ay;
    ((float2*)hout)[(size_t)wid * 64 + lane] = r;
}

// ---------------------------------------------------------------- out = relu(h) @ Wc + bc
__global__ __launch_bounds__(256) void cls_kernel(const float* __restrict__ h,
                                                  const float* __restrict__ Wc,
                                                  const float* __restrict__ bc,
                                                  float* __restrict__ out, int n) {
    __shared__ float wc[NHID * NCLS];
    __shared__ float bcs[NCLS];
    int tid = threadIdx.x;
    for (int i = tid; i < NHID * NCLS; i += 256) wc[i] = Wc[i];
    if (tid < NCLS) bcs[tid] = bc[tid];
    __syncthreads();
    int i = blockIdx.x * 256 + tid;
    if (i >= n) return;
    float acc[NCLS];
#pragma unroll
    for (int c = 0; c < NCLS; ++c) acc[c] = bcs[c];
    const float4* h4 = (const float4*)(h + (size_t)i * NHID);
    for (int k4 = 0; k4 < NHID / 4; ++k4) {
        float4 v = h4[k4];
        float vs[4] = {fmaxf(v.x, 0.f), fmaxf(v.y, 0.f), fmaxf(v.z, 0.f), fmaxf(v.w, 0.f)};
#pragma unroll
        for (int j = 0; j < 4; ++j)
#pragma unroll
            for (int c = 0; c < NCLS; ++c)
                acc[c] = fmaf(vs[j], wc[(k4 * 4 + j) * NCLS + c], acc[c]);
    }
#pragma unroll
    for (int c = 0; c < NCLS; ++c) out[(size_t)i * NCLS + c] = acc[c];
}

// ----------------------------------------------------------------
static inline size_t align256(size_t x) { return (x + 255) & ~(size_t)255; }

extern "C" void kernel_launch(void* const* d_in, const int* in_sizes, int n_in,
                              void* d_out, int out_size, void* d_ws, size_t ws_size,
                              hipStream_t stream) {
    const float* x   = (const float*)d_in[0];
    const int*   ei  = (const int*)d_in[1];     // int64 in reference -> staged as int32
    const float* W1  = (const float*)d_in[2];
    const float* b1  = (const float*)d_in[3];
    const float* Wc  = (const float*)d_in[4];
    const float* bc  = (const float*)d_in[5];
    float*       out = (float*)d_out;

    const int N = in_sizes[0] / NFEAT;     // 50000
    const int E = in_sizes[1] / 2;         // 1600000

    char* ws = (char*)d_ws;
    size_t off = 0;
    float* hA    = (float*)(ws + off); off = align256(off + (size_t)N * NHID * 4);
    float* hB    = (float*)(ws + off); off = align256(off + (size_t)N * NHID * 4);
    int*   cnt   = (int*)  (ws + off); off = align256(off + (size_t)N * 4);
    float* dinv  = (float*)(ws + off); off = align256(off + (size_t)N * 4);
    int*   offs  = (int*)  (ws + off); off = align256(off + (size_t)(N + 1) * 4);
    int*   pos   = (int*)  (ws + off); off = align256(off + (size_t)N * 4);
    int*   esrc  = (int*)  (ws + off); off = align256(off + (size_t)E * 4);
    float* enorm = (float*)(ws + off); off = align256(off + (size_t)E * 4);

    hipMemsetAsync(cnt, 0, (size_t)N * 4, stream);

    deg_kernel<<<(E + 255) / 256, 256, 0, stream>>>(ei, cnt, E);
    dinv_kernel<<<(N + 255) / 256, 256, 0, stream>>>(cnt, dinv, N);
    scan_kernel<<<1, 256, 0, stream>>>(cnt, offs, pos, N);
    scatter_kernel<<<(E + 255) / 256, 256, 0, stream>>>(ei, dinv, pos, esrc, enorm, E);

    gemm1_kernel<<<(N + 63) / 64, 256, 0, stream>>>(x, W1, b1, hA, N);

    for (int i = 0; i < CONV_TIME; ++i) {
        const float* hi = (i & 1) ? hB : hA;
        float*       ho = (i & 1) ? hA : hB;
        hop_kernel<<<(N + 3) / 4, 256, 0, stream>>>(hi, ho, offs, esrc, enorm, dinv, N);
    }

    cls_kernel<<<(N + 255) / 256, 256, 0, stream>>>(hA, Wc, bc, out, N);
}

// Round 3
// 3570.247 us; speedup vs baseline: 1.4384x; 1.4384x over previous
//
#include <hip/hip_runtime.h>
#include <hip/hip_bf16.h>

#define NFEAT 256
#define NHID  128
#define NCLS  10
#define CONV_TIME 30

// ---------------------------------------------------------------- degree histogram
// NOTE: harness stages integer inputs as int32 (NOT int64) — read as int.
__global__ void deg_kernel(const int* __restrict__ ei, int* __restrict__ cnt, int E) {
    int e = blockIdx.x * blockDim.x + threadIdx.x;
    if (e < E) {
        int d = ei[(size_t)E + e];   // edge_index[1][e]
        atomicAdd(&cnt[d], 1);
    }
}

// ---------------------------------------------------------------- dinv = 1/sqrt(deg+1)
__global__ void dinv_kernel(const int* __restrict__ cnt, float* __restrict__ dinv, int n) {
    int i = blockIdx.x * blockDim.x + threadIdx.x;
    if (i < n) {
        float deg = (float)(cnt[i] + 1);   // +1 self loop; always >= 1
        dinv[i] = 1.0f / sqrtf(deg);
    }
}

// ---------------------------------------------------------------- exclusive scan (single block)
__global__ void scan_kernel(const int* __restrict__ cnt, int* __restrict__ offs,
                            int* __restrict__ pos, int n) {
    __shared__ int lds[256];
    int tid = threadIdx.x;
    int per = (n + 255) >> 8;
    int beg = tid * per;
    int end = min(beg + per, n);
    int sum = 0;
    for (int i = beg; i < end; ++i) sum += cnt[i];
    lds[tid] = sum;
    __syncthreads();
    if (tid == 0) {
        int acc = 0;
        for (int i = 0; i < 256; ++i) { int t = lds[i]; lds[i] = acc; acc += t; }
    }
    __syncthreads();
    int run = lds[tid];
    for (int i = beg; i < end; ++i) { offs[i] = run; pos[i] = run; run += cnt[i]; }
    if (tid == 255) offs[n] = run;   // total edge count
}

// ---------------------------------------------------------------- scatter edges into CSR (by dst)
__global__ void scatter_kernel(const int* __restrict__ ei, const float* __restrict__ dinv,
                               int* __restrict__ pos, int* __restrict__ esrc,
                               float* __restrict__ enorm, int E) {
    int e = blockIdx.x * blockDim.x + threadIdx.x;
    if (e < E) {
        int s = ei[e];
        int d = ei[(size_t)E + e];
        int p = atomicAdd(&pos[d], 1);
        esrc[p]  = s;
        enorm[p] = dinv[s] * dinv[d];
    }
}

// ---------------------------------------------------------------- h0 = x @ W1 + b1  (fp32, tiled)
__global__ __launch_bounds__(256) void gemm1_kernel(const float* __restrict__ x,
                                                    const float* __restrict__ W1,
                                                    const float* __restrict__ b1,
                                                    float* __restrict__ h, int M) {
    __shared__ float As[64][20];
    __shared__ float Bs[16][128];
    int tid = threadIdx.x;
    int m0  = blockIdx.x * 64;
    int tx  = tid & 15;
    int ty  = tid >> 4;
    int ar  = tid >> 2, aq = tid & 3;
    int br  = tid >> 4, bc = tid & 15;

    float acc[4][8];
#pragma unroll
    for (int i = 0; i < 4; ++i)
#pragma unroll
        for (int j = 0; j < 8; ++j) acc[i][j] = 0.0f;

    for (int kb = 0; kb < NFEAT; kb += 16) {
        float4 av = make_float4(0.f, 0.f, 0.f, 0.f);
        int arow = m0 + ar;
        if (arow < M) av = *(const float4*)(x + (size_t)arow * NFEAT + kb + aq * 4);
        *(float4*)&As[ar][aq * 4] = av;
        *(float4*)&Bs[br][bc * 8]     = *(const float4*)(W1 + (size_t)(kb + br) * NHID + bc * 8);
        *(float4*)&Bs[br][bc * 8 + 4] = *(const float4*)(W1 + (size_t)(kb + br) * NHID + bc * 8 + 4);
        __syncthreads();
#pragma unroll
        for (int k = 0; k < 16; ++k) {
            float a0 = As[ty * 4 + 0][k];
            float a1 = As[ty * 4 + 1][k];
            float a2 = As[ty * 4 + 2][k];
            float a3 = As[ty * 4 + 3][k];
            float4 b0 = *(float4*)&Bs[k][tx * 8];
            float4 b1v = *(float4*)&Bs[k][tx * 8 + 4];
            float bv[8] = {b0.x, b0.y, b0.z, b0.w, b1v.x, b1v.y, b1v.z, b1v.w};
            float avv[4] = {a0, a1, a2, a3};
#pragma unroll
            for (int i = 0; i < 4; ++i)
#pragma unroll
                for (int j = 0; j < 8; ++j)
                    acc[i][j] = fmaf(avv[i], bv[j], acc[i][j]);
        }
        __syncthreads();
    }
#pragma unroll
    for (int i = 0; i < 4; ++i) {
        int row = m0 + ty * 4 + i;
        if (row < M) {
#pragma unroll
            for (int j = 0; j < 8; ++j)
                h[(size_t)row * NHID + tx * 8 + j] = acc[i][j] + b1[tx * 8 + j];
        }
    }
}

// ---------------------------------------------------------------- one propagation hop
// One wave64 per node; lane holds features [2*lane, 2*lane+1].
// Edge metadata is loaded 64-at-a-time coalesced (one edge per lane) and
// broadcast via __shfl, so the per-edge dependent chain is ONLY the h gather.
// Gathers are unrolled x8 so up to 8 float2 loads are in flight per wave.
__global__ __launch_bounds__(256) void hop_kernel(const float* __restrict__ hin,
                                                  float* __restrict__ hout,
                                                  const int* __restrict__ offs,
                                                  const int* __restrict__ esrc,
                                                  const float* __restrict__ enorm,
                                                  const float* __restrict__ dinv, int n) {
    int wid  = blockIdx.x * 4 + (threadIdx.x >> 6);
    int lane = threadIdx.x & 63;
    if (wid >= n) return;
    int beg = offs[wid];
    int end = offs[wid + 1];
    const float2* __restrict__ hin2 = (const float2*)hin;
    float2 self = hin2[(size_t)wid * 64 + lane];
    float dv = dinv[wid];
    float w0 = dv * dv;
    float ax = self.x * w0;
    float ay = self.y * w0;

    for (int e0 = beg; e0 < end; e0 += 64) {
        int cs = end - e0; if (cs > 64) cs = 64;
        int   sv = 0;
        float wv = 0.0f;
        if (lane < cs) {
            sv = esrc[e0 + lane];
            wv = enorm[e0 + lane];
        }
        int i = 0;
        for (; i + 8 <= cs; i += 8) {
#pragma unroll
            for (int j = 0; j < 8; ++j) {
                int   s = __shfl(sv, i + j, 64);
                float w = __shfl(wv, i + j, 64);
                float2 v = hin2[(size_t)s * 64 + lane];
                ax = fmaf(w, v.x, ax);
                ay = fmaf(w, v.y, ay);
            }
        }
        for (; i < cs; ++i) {
            int   s = __shfl(sv, i, 64);
            float w = __shfl(wv, i, 64);
            float2 v = hin2[(size_t)s * 64 + lane];
            ax = fmaf(w, v.x, ax);
            ay = fmaf(w, v.y, ay);
        }
    }
    float2 r; r.x = ax; r.y = ay;
    ((float2*)hout)[(size_t)wid * 64 + lane] = r;
}

// ---------------------------------------------------------------- out = relu(h) @ Wc + bc
__global__ __launch_bounds__(256) void cls_kernel(const float* __restrict__ h,
                                                  const float* __restrict__ Wc,
                                                  const float* __restrict__ bc,
                                                  float* __restrict__ out, int n) {
    __shared__ float wc[NHID * NCLS];
    __shared__ float bcs[NCLS];
    int tid = threadIdx.x;
    for (int i = tid; i < NHID * NCLS; i += 256) wc[i] = Wc[i];
    if (tid < NCLS) bcs[tid] = bc[tid];
    __syncthreads();
    int i = blockIdx.x * 256 + tid;
    if (i >= n) return;
    float acc[NCLS];
#pragma unroll
    for (int c = 0; c < NCLS; ++c) acc[c] = bcs[c];
    const float4* h4 = (const float4*)(h + (size_t)i * NHID);
    for (int k4 = 0; k4 < NHID / 4; ++k4) {
        float4 v = h4[k4];
        float vs[4] = {fmaxf(v.x, 0.f), fmaxf(v.y, 0.f), fmaxf(v.z, 0.f), fmaxf(v.w, 0.f)};
#pragma unroll
        for (int j = 0; j < 4; ++j)
#pragma unroll
            for (int c = 0; c < NCLS; ++c)
                acc[c] = fmaf(vs[j], wc[(k4 * 4 + j) * NCLS + c], acc[c]);
    }
#pragma unroll
    for (int c = 0; c < NCLS; ++c) out[(size_t)i * NCLS + c] = acc[c];
}

// ----------------------------------------------------------------
static inline size_t align256(size_t x) { return (x + 255) & ~(size_t)255; }

extern "C" void kernel_launch(void* const* d_in, const int* in_sizes, int n_in,
                              void* d_out, int out_size, void* d_ws, size_t ws_size,
                              hipStream_t stream) {
    const float* x   = (const float*)d_in[0];
    const int*   ei  = (const int*)d_in[1];     // int64 in reference -> staged as int32
    const float* W1  = (const float*)d_in[2];
    const float* b1  = (const float*)d_in[3];
    const float* Wc  = (const float*)d_in[4];
    const float* bc  = (const float*)d_in[5];
    float*       out = (float*)d_out;

    const int N = in_sizes[0] / NFEAT;     // 50000
    const int E = in_sizes[1] / 2;         // 1600000

    char* ws = (char*)d_ws;
    size_t off = 0;
    float* hA    = (float*)(ws + off); off = align256(off + (size_t)N * NHID * 4);
    float* hB    = (float*)(ws + off); off = align256(off + (size_t)N * NHID * 4);
    int*   cnt   = (int*)  (ws + off); off = align256(off + (size_t)N * 4);
    float* dinv  = (float*)(ws + off); off = align256(off + (size_t)N * 4);
    int*   offs  = (int*)  (ws + off); off = align256(off + (size_t)(N + 1) * 4);
    int*   pos   = (int*)  (ws + off); off = align256(off + (size_t)N * 4);
    int*   esrc  = (int*)  (ws + off); off = align256(off + (size_t)E * 4);
    float* enorm = (float*)(ws + off); off = align256(off + (size_t)E * 4);

    hipMemsetAsync(cnt, 0, (size_t)N * 4, stream);

    deg_kernel<<<(E + 255) / 256, 256, 0, stream>>>(ei, cnt, E);
    dinv_kernel<<<(N + 255) / 256, 256, 0, stream>>>(cnt, dinv, N);
    scan_kernel<<<1, 256, 0, stream>>>(cnt, offs, pos, N);
    scatter_kernel<<<(E + 255) / 256, 256, 0, stream>>>(ei, dinv, pos, esrc, enorm, E);

    gemm1_kernel<<<(N + 63) / 64, 256, 0, stream>>>(x, W1, b1, hA, N);

    for (int i = 0; i < CONV_TIME; ++i) {
        const float* hi = (i & 1) ? hB : hA;
        float*       ho = (i & 1) ? hA : hB;
        hop_kernel<<<(N + 3) / 4, 256, 0, stream>>>(hi, ho, offs, esrc, enorm, dinv, N);
    }

    cls_kernel<<<(N + 255) / 256, 256, 0, stream>>>(hA, Wc, bc, out, N);
}